// Round 6
// baseline (689.838 us; speedup 1.0000x reference)
//
#include <hip/hip_runtime.h>

#define NN 50000
#define NE 800000

typedef __attribute__((ext_vector_type(4))) float vf32x4;
typedef __attribute__((ext_vector_type(8))) __bf16 vbf16x8;
typedef __attribute__((ext_vector_type(4))) unsigned short vushort4;
typedef __attribute__((ext_vector_type(8))) unsigned short vushort8;

// ---- workspace layout (bytes), total ~46.0 MB ----
constexpr size_t OFF_AGG  = 0;                 // 25,600,000 (f32 agg)
constexpr size_t OFF_CNT  = 25600000;          // 200,000 (int histogram counts)
constexpr size_t OFF_DX   = 25800000;          // 600,000 (f32 dx sums)
constexpr size_t ZBYTES   = 26400000;          // zero agg+cnt+dx
constexpr size_t OFF_OFFS = 26400000;          // 200,000 (int scan offsets)
constexpr size_t OFF_BSUM = 26600000;          // 4,096
constexpr size_t OFF_BPRE = 26604096;          // 4,096
constexpr size_t OFF_RC2  = 26608192;          // 6,400,000 (int2 sorted (row,col))
constexpr size_t OFF_HBF  = 33008192;          // 12,800,000 (h bf16)
constexpr size_t OFF_WE1P = 45808192;          // 65,536
constexpr size_t OFF_WE2P = OFF_WE1P + 65536;
constexpr size_t OFF_WC1P = OFF_WE2P + 32768;
constexpr size_t OFF_WN1P = OFF_WC1P + 32768;
constexpr size_t OFF_WN2P = OFF_WN1P + 65536;

__device__ __forceinline__ unsigned short f2bf(float f) {
    unsigned int u = __float_as_uint(f);
    u += 0x7fffu + ((u >> 16) & 1u);
    return (unsigned short)(u >> 16);
}

__device__ __forceinline__ float silu(float v) {
    return __fdividef(v, 1.0f + __expf(-v));
}

// ---- h (f32) -> h_bf (bf16) ----
__global__ __launch_bounds__(256) void h2bf_kernel(const float* __restrict__ h,
                                                   unsigned short* __restrict__ h_bf) {
    int idx = blockIdx.x * 256 + threadIdx.x;
    vf32x4 v = ((const vf32x4*)h)[idx];
    vushort4 o;
    o[0] = f2bf(v[0]); o[1] = f2bf(v[1]); o[2] = f2bf(v[2]); o[3] = f2bf(v[3]);
    ((vushort4*)h_bf)[idx] = o;
}

// ---- pack weight [K x 128] f32 into per-lane B-fragment bf16 layout ----
__device__ __forceinline__ void pack_one(const float* __restrict__ src,
                                         unsigned short* __restrict__ dst,
                                         int local, int KB) {
    int j = local & 7;
    int lane = (local >> 3) & 63;
    int rest = local >> 9;
    int kb = rest % KB;
    int t = rest / KB;
    int srow = kb * 32 + ((lane >> 4) << 3) + j;
    int scol = t * 16 + (lane & 15);
    dst[local] = f2bf(src[srow * 128 + scol]);
}

__global__ __launch_bounds__(256) void pack_w_kernel(
    const float* __restrict__ We1, const float* __restrict__ We2,
    const float* __restrict__ Wc1, const float* __restrict__ Wn1,
    const float* __restrict__ Wn2,
    unsigned short* __restrict__ We1p, unsigned short* __restrict__ We2p,
    unsigned short* __restrict__ Wc1p, unsigned short* __restrict__ Wn1p,
    unsigned short* __restrict__ Wn2p) {
    int idx = blockIdx.x * 256 + threadIdx.x;
    if (idx < 32768)       pack_one(We1, We1p, idx, 8);
    else if (idx < 49152)  pack_one(We2, We2p, idx - 32768, 4);
    else if (idx < 65536)  pack_one(Wc1, Wc1p, idx - 49152, 4);
    else if (idx < 98304)  pack_one(Wn1, Wn1p, idx - 65536, 8);
    else                   pack_one(Wn2, Wn2p, idx - 98304, 4);
}

// ---- histogram of edge rows ----
__global__ __launch_bounds__(256) void hist_kernel(const int* __restrict__ ei,
                                                   int* __restrict__ cnt) {
    int e = blockIdx.x * 256 + threadIdx.x;
    if (e < NE) atomicAdd(&cnt[ei[e]], 1);
}

// ---- 3-kernel parallel exclusive scan of cnt[NN] ----
__global__ __launch_bounds__(256) void scanA_kernel(const int* __restrict__ cnt,
                                                    int* __restrict__ bsum) {
    __shared__ int wsum[4];
    int tid = threadIdx.x, lane = tid & 63, w = tid >> 6;
    int base = blockIdx.x * 1024 + tid * 4;
    int s4 = 0;
#pragma unroll
    for (int j = 0; j < 4; j++) s4 += (base + j < NN) ? cnt[base + j] : 0;
    int s = s4;
#pragma unroll
    for (int d = 1; d < 64; d <<= 1) s += __shfl_xor(s, d, 64);
    if (lane == 0) wsum[w] = s;
    __syncthreads();
    if (tid == 0) bsum[blockIdx.x] = wsum[0] + wsum[1] + wsum[2] + wsum[3];
}

__global__ __launch_bounds__(64) void scanB_kernel(const int* __restrict__ bsum,
                                                   int* __restrict__ bpre) {
    int lane = threadIdx.x;
    int v = (lane < 49) ? bsum[lane] : 0;
    int s = v;
#pragma unroll
    for (int d = 1; d < 64; d <<= 1) {
        int t2 = __shfl_up(s, d, 64);
        if (lane >= d) s += t2;
    }
    if (lane < 49) bpre[lane] = s - v;
}

__global__ __launch_bounds__(256) void scanC_kernel(const int* __restrict__ cnt,
                                                    const int* __restrict__ bpre,
                                                    int* __restrict__ offs) {
    __shared__ int wsum[4];
    int tid = threadIdx.x, lane = tid & 63, w = tid >> 6;
    int base = blockIdx.x * 1024 + tid * 4;
    int c[4];
    int s4 = 0;
#pragma unroll
    for (int j = 0; j < 4; j++) {
        c[j] = (base + j < NN) ? cnt[base + j] : 0;
        s4 += c[j];
    }
    int s = s4;
#pragma unroll
    for (int d = 1; d < 64; d <<= 1) {
        int t2 = __shfl_up(s, d, 64);
        if (lane >= d) s += t2;
    }
    if (lane == 63) wsum[w] = s;
    __syncthreads();
    int wbase = 0;
#pragma unroll
    for (int k = 0; k < 4; k++) wbase += (k < w) ? wsum[k] : 0;
    int excl = bpre[blockIdx.x] + wbase + (s - s4);
#pragma unroll
    for (int j = 0; j < 4; j++) {
        if (base + j < NN) { offs[base + j] = excl; excl += c[j]; }
    }
}

// ---- scatter: materialize row-sorted (row,col) pairs ----
__global__ __launch_bounds__(256) void scatter_kernel(const int* __restrict__ ei,
                                                      int* __restrict__ offs,
                                                      int2* __restrict__ rc2) {
    int e = blockIdx.x * 256 + threadIdx.x;
    if (e < NE) {
        int r = ei[e], c = ei[NE + e];
        int p = atomicAdd(&offs[r], 1);
        rc2[p] = make_int2(r, c);
    }
}

__device__ __forceinline__ void scatter_agg(float* __restrict__ agg,
                                            const int* __restrict__ s_row,
                                            const vf32x4 (&a)[8], int q0, int li) {
    int cur = s_row[q0];
    float av[8];
#pragma unroll
    for (int t = 0; t < 8; t++) av[t] = a[t][0];
#pragma unroll
    for (int r = 1; r < 4; r++) {
        int rw = s_row[q0 + r];
        if (rw != cur) {           // uniform within the 16-lane quad
#pragma unroll
            for (int t = 0; t < 8; t++) {
                atomicAdd(&agg[(size_t)cur * 128 + t * 16 + li], av[t]);
                av[t] = a[t][r];
            }
            cur = rw;
        } else {
#pragma unroll
            for (int t = 0; t < 8; t++) av[t] += a[t][r];
        }
    }
#pragma unroll
    for (int t = 0; t < 8; t++)
        atomicAdd(&agg[(size_t)cur * 128 + t * 16 + li], av[t]);
}

__device__ __forceinline__ void scatter_dx(float* __restrict__ dxsum,
                                           const int* __restrict__ s_row,
                                           const float* __restrict__ s_rel,
                                           const float (&gp)[4], int q0, int li) {
    if (li >= 3) return;
    int cur = s_row[q0];
    float dxa = s_rel[q0 * 4 + li] * gp[0];
#pragma unroll
    for (int r = 1; r < 4; r++) {
        int rw = s_row[q0 + r];
        if (rw != cur) {
            atomicAdd(&dxsum[cur * 3 + li], dxa);
            dxa = s_rel[(q0 + r) * 4 + li] * gp[r];
            cur = rw;
        } else {
            dxa += s_rel[(q0 + r) * 4 + li] * gp[r];
        }
    }
    atomicAdd(&dxsum[cur * 3 + li], dxa);
}

// ---- edge kernel: 128 sorted edges/block; each wave = 2 row-tiles sharing B ----
__global__ __launch_bounds__(256, 3) void edge_kernel(
    const float* __restrict__ x, const int2* __restrict__ rc2,
    const unsigned short* __restrict__ h_bf,
    const unsigned short* __restrict__ We1p, const unsigned short* __restrict__ We2p,
    const unsigned short* __restrict__ Wc1p,
    const float* __restrict__ We1, const float* __restrict__ be1,
    const float* __restrict__ be2, const float* __restrict__ bc1,
    const float* __restrict__ Wc2, const float* __restrict__ bc2,
    float* __restrict__ dxsum, float* __restrict__ agg) {

    __shared__ __align__(16) unsigned short s_ef[128 * 136];  // 34,816 B (wave-local rows)
    __shared__ float s_rel[128 * 4];
    __shared__ int s_row[128];
    __shared__ int s_col[128];

    const int tid = threadIdx.x;
    const int ebase = blockIdx.x * 128;

    if (tid < 128) {
        int2 rc = rc2[ebase + tid];
        int r = rc.x, c = rc.y;
        s_row[tid] = r;
        s_col[tid] = c;
        float d0 = x[r * 3 + 0] - x[c * 3 + 0];
        float d1 = x[r * 3 + 1] - x[c * 3 + 1];
        float d2v = x[r * 3 + 2] - x[c * 3 + 2];
        s_rel[tid * 4 + 0] = d0;
        s_rel[tid * 4 + 1] = d1;
        s_rel[tid * 4 + 2] = d2v;
        s_rel[tid * 4 + 3] = d0 * d0 + d1 * d1 + d2v * d2v;
    }
    __syncthreads();   // the ONLY barrier: everything below is wave-local in LDS

    const int wave = tid >> 6, lane = tid & 63;
    const int li = lane & 15, grp = lane >> 4;
    const int e0 = wave * 32 + li;       // tile0 A-row edge
    const int e1 = e0 + 16;              // tile1 A-row edge
    const vf32x4 vzero = {0.f, 0.f, 0.f, 0.f};

    vf32x4 acc0[8], acc1[8];
#pragma unroll
    for (int t = 0; t < 8; t++) { acc0[t] = vzero; acc1[t] = vzero; }

    // ---- layer 1, half-pass A: k in [0,128) from h[row] ----
    {
        vbf16x8 a0[4], a1[4];
        const unsigned short* p0 = h_bf + (size_t)s_row[e0] * 128 + grp * 8;
        const unsigned short* p1 = h_bf + (size_t)s_row[e1] * 128 + grp * 8;
#pragma unroll
        for (int kb = 0; kb < 4; kb++) {
            a0[kb] = *(const vbf16x8*)(p0 + kb * 32);
            a1[kb] = *(const vbf16x8*)(p1 + kb * 32);
        }
#pragma unroll
        for (int kb = 0; kb < 4; kb++) {
#pragma unroll
            for (int t = 0; t < 8; t++) {
                vbf16x8 b = *(const vbf16x8*)(We1p + ((t * 8 + kb) * 64 + lane) * 8);
                acc0[t] = __builtin_amdgcn_mfma_f32_16x16x32_bf16(a0[kb], b, acc0[t], 0, 0, 0);
                acc1[t] = __builtin_amdgcn_mfma_f32_16x16x32_bf16(a1[kb], b, acc1[t], 0, 0, 0);
            }
        }
    }
    // ---- layer 1, half-pass B: k in [128,256) from h[col] ----
    {
        vbf16x8 a0[4], a1[4];
        const unsigned short* p0 = h_bf + (size_t)s_col[e0] * 128 + grp * 8;
        const unsigned short* p1 = h_bf + (size_t)s_col[e1] * 128 + grp * 8;
#pragma unroll
        for (int kb = 0; kb < 4; kb++) {
            a0[kb] = *(const vbf16x8*)(p0 + kb * 32);
            a1[kb] = *(const vbf16x8*)(p1 + kb * 32);
        }
#pragma unroll
        for (int kb = 0; kb < 4; kb++) {
#pragma unroll
            for (int t = 0; t < 8; t++) {
                vbf16x8 b = *(const vbf16x8*)(We1p + ((t * 8 + kb + 4) * 64 + lane) * 8);
                acc0[t] = __builtin_amdgcn_mfma_f32_16x16x32_bf16(a0[kb], b, acc0[t], 0, 0, 0);
                acc1[t] = __builtin_amdgcn_mfma_f32_16x16x32_bf16(a1[kb], b, acc1[t], 0, 0, 0);
            }
        }
    }

    // ---- layer-1 epilogue -> s_ef ----
    float d2a[4], d2b[4];
#pragma unroll
    for (int r = 0; r < 4; r++) {
        d2a[r] = s_rel[(wave * 32 + grp * 4 + r) * 4 + 3];
        d2b[r] = s_rel[(wave * 32 + 16 + grp * 4 + r) * 4 + 3];
    }
#pragma unroll
    for (int t = 0; t < 8; t++) {
        int col = t * 16 + li;
        float b1 = be1[col], wl = We1[256 * 128 + col];
#pragma unroll
        for (int r = 0; r < 4; r++) {
            float v0 = silu(acc0[t][r] + b1 + d2a[r] * wl);
            s_ef[(wave * 32 + grp * 4 + r) * 136 + col] = f2bf(v0);
            float v1 = silu(acc1[t][r] + b1 + d2b[r] * wl);
            s_ef[(wave * 32 + 16 + grp * 4 + r) * 136 + col] = f2bf(v1);
        }
    }

    // ---- layer 2 (wave-local s_ef; no barrier) ----
#pragma unroll
    for (int t = 0; t < 8; t++) { acc0[t] = vzero; acc1[t] = vzero; }
    {
        const unsigned short* arow0 = s_ef + (size_t)(wave * 32 + li) * 136 + grp * 8;
        const unsigned short* arow1 = arow0 + 16 * 136;
#pragma unroll
        for (int kb = 0; kb < 4; kb++) {
            vbf16x8 a0 = *(const vbf16x8*)(arow0 + kb * 32);
            vbf16x8 a1 = *(const vbf16x8*)(arow1 + kb * 32);
#pragma unroll
            for (int t = 0; t < 8; t++) {
                vbf16x8 b = *(const vbf16x8*)(We2p + ((t * 4 + kb) * 64 + lane) * 8);
                acc0[t] = __builtin_amdgcn_mfma_f32_16x16x32_bf16(a0, b, acc0[t], 0, 0, 0);
                acc1[t] = __builtin_amdgcn_mfma_f32_16x16x32_bf16(a1, b, acc1[t], 0, 0, 0);
            }
        }
    }
    // silu in place (acc now holds ef, f32) + store bf16 for gate input
#pragma unroll
    for (int t = 0; t < 8; t++) {
        int col = t * 16 + li;
        float b2 = be2[col];
#pragma unroll
        for (int r = 0; r < 4; r++) {
            acc0[t][r] = silu(acc0[t][r] + b2);
            s_ef[(wave * 32 + grp * 4 + r) * 136 + col] = f2bf(acc0[t][r]);
            acc1[t][r] = silu(acc1[t][r] + b2);
            s_ef[(wave * 32 + 16 + grp * 4 + r) * 136 + col] = f2bf(acc1[t][r]);
        }
    }

    // ---- agg scatter from registers (before gate reuses acc) ----
    scatter_agg(agg, s_row, acc0, wave * 32 + grp * 4, li);
    scatter_agg(agg, s_row, acc1, wave * 32 + 16 + grp * 4, li);

    // ---- gate GEMM ----
#pragma unroll
    for (int t = 0; t < 8; t++) { acc0[t] = vzero; acc1[t] = vzero; }
    {
        const unsigned short* arow0 = s_ef + (size_t)(wave * 32 + li) * 136 + grp * 8;
        const unsigned short* arow1 = arow0 + 16 * 136;
#pragma unroll
        for (int kb = 0; kb < 4; kb++) {
            vbf16x8 a0 = *(const vbf16x8*)(arow0 + kb * 32);
            vbf16x8 a1 = *(const vbf16x8*)(arow1 + kb * 32);
#pragma unroll
            for (int t = 0; t < 8; t++) {
                vbf16x8 b = *(const vbf16x8*)(Wc1p + ((t * 4 + kb) * 64 + lane) * 8);
                acc0[t] = __builtin_amdgcn_mfma_f32_16x16x32_bf16(a0, b, acc0[t], 0, 0, 0);
                acc1[t] = __builtin_amdgcn_mfma_f32_16x16x32_bf16(a1, b, acc1[t], 0, 0, 0);
            }
        }
    }
    float gp0[4] = {0.f, 0.f, 0.f, 0.f}, gp1[4] = {0.f, 0.f, 0.f, 0.f};
#pragma unroll
    for (int t = 0; t < 8; t++) {
        int col = t * 16 + li;
        float bc = bc1[col], w2 = Wc2[col];
#pragma unroll
        for (int r = 0; r < 4; r++) {
            gp0[r] += silu(acc0[t][r] + bc) * w2;
            gp1[r] += silu(acc1[t][r] + bc) * w2;
        }
    }
    const float bc2v = bc2[0];
#pragma unroll
    for (int r = 0; r < 4; r++) {
#pragma unroll
        for (int d = 1; d < 16; d <<= 1) {
            gp0[r] += __shfl_xor(gp0[r], d, 16);
            gp1[r] += __shfl_xor(gp1[r], d, 16);
        }
        gp0[r] += bc2v;
        gp1[r] += bc2v;
    }

    // ---- dx scatter ----
    scatter_dx(dxsum, s_row, s_rel, gp0, wave * 32 + grp * 4, li);
    scatter_dx(dxsum, s_row, s_rel, gp1, wave * 32 + 16 + grp * 4, li);
}

// ---- node kernel: 64 nodes per block ----
__global__ __launch_bounds__(256, 4) void node_kernel(
    const float* __restrict__ x, const float* __restrict__ h32,
    const unsigned short* __restrict__ h_bf,
    const int* __restrict__ cnt, const float* __restrict__ dxsum,
    const float* __restrict__ agg,
    const unsigned short* __restrict__ Wn1p, const unsigned short* __restrict__ Wn2p,
    const float* __restrict__ bn1, const float* __restrict__ bn2,
    const float* __restrict__ gamma, const float* __restrict__ beta,
    float* __restrict__ out) {

    __shared__ __align__(16) unsigned short s_agg[64 * 136];
    __shared__ __align__(16) unsigned short s_ef[64 * 136];

    const int tid = threadIdx.x;
    const int nbase = blockIdx.x * 64;

    // x_out = x + dx/cnt
    {
        int idx = blockIdx.x * 192 + tid;
        if (tid < 192 && idx < NN * 3) {
            int node = idx / 3;
            float cf = fmaxf((float)cnt[node], 1.0f);
            out[idx] = x[idx] + dxsum[idx] / cf;
        }
    }
    // stage agg (f32 -> bf16, divided by count)
#pragma unroll
    for (int i = 0; i < 8; i++) {
        int flat = i * 256 + tid;
        int row = flat >> 5, q = flat & 31;
        int node = nbase + row;
        if (node >= NN) node = NN - 1;
        float inv = 1.0f / fmaxf((float)cnt[node], 1.0f);
        vf32x4 v = *(const vf32x4*)(agg + (size_t)node * 128 + q * 4);
        vushort4 o;
        o[0] = f2bf(v[0] * inv); o[1] = f2bf(v[1] * inv);
        o[2] = f2bf(v[2] * inv); o[3] = f2bf(v[3] * inv);
        *(vushort4*)(&s_agg[row * 136 + q * 4]) = o;
    }
    __syncthreads();

    const int wave = tid >> 6, lane = tid & 63;
    const int li = lane & 15, grp = lane >> 4;
    const vf32x4 vzero = {0.f, 0.f, 0.f, 0.f};

    int mynode = nbase + wave * 16 + li;
    if (mynode >= NN) mynode = NN - 1;

    vbf16x8 af[8];
    {
        const unsigned short* ph = h_bf + (size_t)mynode * 128 + grp * 8;
#pragma unroll
        for (int kb = 0; kb < 4; kb++) af[kb] = *(const vbf16x8*)(ph + kb * 32);
        const unsigned short* pa = s_agg + (wave * 16 + li) * 136 + grp * 8;
#pragma unroll
        for (int kb = 0; kb < 4; kb++) af[4 + kb] = *(const vbf16x8*)(pa + kb * 32);
    }
    vf32x4 acc[8];
#pragma unroll
    for (int t = 0; t < 8; t++) acc[t] = vzero;
#pragma unroll
    for (int kb = 0; kb < 8; kb++) {
#pragma unroll
        for (int t = 0; t < 8; t++) {
            vbf16x8 b = *(const vbf16x8*)(Wn1p + ((t * 8 + kb) * 64 + lane) * 8);
            acc[t] = __builtin_amdgcn_mfma_f32_16x16x32_bf16(af[kb], b, acc[t], 0, 0, 0);
        }
    }
#pragma unroll
    for (int t = 0; t < 8; t++) {
        int col = t * 16 + li;
        float b1 = bn1[col];
#pragma unroll
        for (int r = 0; r < 4; r++) {
            float v = silu(acc[t][r] + b1);
            s_ef[(wave * 16 + grp * 4 + r) * 136 + col] = f2bf(v);
        }
    }
    // no barrier: s_ef rows are wave-local

#pragma unroll
    for (int t = 0; t < 8; t++) acc[t] = vzero;
    {
        const unsigned short* arow = s_ef + (wave * 16 + li) * 136 + grp * 8;
#pragma unroll
        for (int kb = 0; kb < 4; kb++) {
            vbf16x8 a = *(const vbf16x8*)(arow + kb * 32);
#pragma unroll
            for (int t = 0; t < 8; t++) {
                vbf16x8 b = *(const vbf16x8*)(Wn2p + ((t * 4 + kb) * 64 + lane) * 8);
                acc[t] = __builtin_amdgcn_mfma_f32_16x16x32_bf16(a, b, acc[t], 0, 0, 0);
            }
        }
    }
    float h2v[8][4];
    float sum[4] = {0.f, 0.f, 0.f, 0.f}, sq[4] = {0.f, 0.f, 0.f, 0.f};
#pragma unroll
    for (int t = 0; t < 8; t++) {
        int col = t * 16 + li;
        float b2 = bn2[col];
#pragma unroll
        for (int r = 0; r < 4; r++) {
            int node = nbase + wave * 16 + grp * 4 + r;
            int nc = node < NN ? node : NN - 1;
            float v = acc[t][r] + b2 + h32[(size_t)nc * 128 + col];
            h2v[t][r] = v;
            sum[r] += v;
            sq[r] += v * v;
        }
    }
    float mu[4], rstd[4];
#pragma unroll
    for (int r = 0; r < 4; r++) {
#pragma unroll
        for (int d = 1; d < 16; d <<= 1) {
            sum[r] += __shfl_xor(sum[r], d, 16);
            sq[r] += __shfl_xor(sq[r], d, 16);
        }
        mu[r] = sum[r] * (1.0f / 128.0f);
        float var = sq[r] * (1.0f / 128.0f) - mu[r] * mu[r];
        rstd[r] = rsqrtf(var + 1e-5f);
    }
#pragma unroll
    for (int t = 0; t < 8; t++) {
        int col = t * 16 + li;
        float g = gamma[col], bt = beta[col];
#pragma unroll
        for (int r = 0; r < 4; r++) {
            int node = nbase + wave * 16 + grp * 4 + r;
            if (node < NN) {
                float vn = (h2v[t][r] - mu[r]) * rstd[r] * g + bt;
                out[NN * 3 + (size_t)node * 128 + col] = silu(vn);
            }
        }
    }
}

extern "C" void kernel_launch(void* const* d_in, const int* in_sizes, int n_in,
                              void* d_out, int out_size, void* d_ws, size_t ws_size,
                              hipStream_t stream) {
    const float* x     = (const float*)d_in[0];
    const float* h     = (const float*)d_in[1];
    const int* ei      = (const int*)d_in[2];
    const float* We1   = (const float*)d_in[3];
    const float* be1   = (const float*)d_in[4];
    const float* We2   = (const float*)d_in[5];
    const float* be2   = (const float*)d_in[6];
    const float* Wc1   = (const float*)d_in[7];
    const float* bc1   = (const float*)d_in[8];
    const float* Wc2   = (const float*)d_in[9];
    const float* bc2   = (const float*)d_in[10];
    const float* Wn1   = (const float*)d_in[11];
    const float* bn1   = (const float*)d_in[12];
    const float* Wn2   = (const float*)d_in[13];
    const float* bn2   = (const float*)d_in[14];
    const float* gamma = (const float*)d_in[15];
    const float* beta  = (const float*)d_in[16];
    float* out = (float*)d_out;

    char* ws = (char*)d_ws;
    float* agg            = (float*)(ws + OFF_AGG);
    int* cnt              = (int*)(ws + OFF_CNT);
    float* dxsum          = (float*)(ws + OFF_DX);
    int* offs             = (int*)(ws + OFF_OFFS);
    int* bsum             = (int*)(ws + OFF_BSUM);
    int* bpre             = (int*)(ws + OFF_BPRE);
    int2* rc2             = (int2*)(ws + OFF_RC2);
    unsigned short* h_bf  = (unsigned short*)(ws + OFF_HBF);
    unsigned short* We1p  = (unsigned short*)(ws + OFF_WE1P);
    unsigned short* We2p  = (unsigned short*)(ws + OFF_WE2P);
    unsigned short* Wc1p  = (unsigned short*)(ws + OFF_WC1P);
    unsigned short* Wn1p  = (unsigned short*)(ws + OFF_WN1P);
    unsigned short* Wn2p  = (unsigned short*)(ws + OFF_WN2P);

    hipMemsetAsync(ws, 0, ZBYTES, stream);
    h2bf_kernel<<<6250, 256, 0, stream>>>(h, h_bf);
    pack_w_kernel<<<448, 256, 0, stream>>>(We1, We2, Wc1, Wn1, Wn2,
                                           We1p, We2p, Wc1p, Wn1p, Wn2p);
    hist_kernel<<<NE / 256, 256, 0, stream>>>(ei, cnt);
    scanA_kernel<<<49, 256, 0, stream>>>(cnt, bsum);
    scanB_kernel<<<1, 64, 0, stream>>>(bsum, bpre);
    scanC_kernel<<<49, 256, 0, stream>>>(cnt, bpre, offs);
    scatter_kernel<<<NE / 256, 256, 0, stream>>>(ei, offs, rc2);
    edge_kernel<<<NE / 128, 256, 0, stream>>>(x, rc2, h_bf, We1p, We2p, Wc1p,
                                              We1, be1, be2, bc1, Wc2, bc2,
                                              dxsum, agg);
    node_kernel<<<(NN + 63) / 64, 256, 0, stream>>>(x, h, h_bf, cnt, dxsum, agg,
                                                    Wn1p, Wn2p, bn1, bn2, gamma, beta, out);
}

// Round 7
// 677.099 us; speedup vs baseline: 1.0188x; 1.0188x over previous
//
#include <hip/hip_runtime.h>

#define NN 50000
#define NE 800000

typedef __attribute__((ext_vector_type(4))) float vf32x4;
typedef __attribute__((ext_vector_type(8))) __bf16 vbf16x8;
typedef __attribute__((ext_vector_type(4))) unsigned short vushort4;
typedef __attribute__((ext_vector_type(8))) unsigned short vushort8;

// ---- workspace layout (bytes), total ~39.4 MB ----
constexpr size_t OFF_AGG  = 0;                       // 25,600,000 (f32 agg)
constexpr size_t OFF_CNT  = 25600000;                // 200,000 (int counts)
constexpr size_t OFF_DX   = 25800000;                // 600,000 (f32 dx)
constexpr size_t ZBYTES   = 26400000;                // zero agg+cnt+dx
constexpr size_t OFF_HBF  = 26400000;                // 12,800,000 (h bf16)
constexpr size_t OFF_WE1P = 39200000;                // 65536
constexpr size_t OFF_WE2P = OFF_WE1P + 65536;
constexpr size_t OFF_WC1P = OFF_WE2P + 32768;
constexpr size_t OFF_WN1P = OFF_WC1P + 32768;
constexpr size_t OFF_WN2P = OFF_WN1P + 65536;

// native f32->bf16 (RNE): gfx950 lowers fptrunc to HW cvt; worst case same cost
__device__ __forceinline__ unsigned short f2bf(float f) {
    union { __bf16 h; unsigned short u; } c;
    c.h = (__bf16)f;
    return c.u;
}

__device__ __forceinline__ float silu(float v) {
    return __fdividef(v, 1.0f + __expf(-v));
}

// ---- h (f32) -> h_bf (bf16) ----
__global__ __launch_bounds__(256) void h2bf_kernel(const float* __restrict__ h,
                                                   unsigned short* __restrict__ h_bf) {
    int idx = blockIdx.x * 256 + threadIdx.x;
    vf32x4 v = ((const vf32x4*)h)[idx];
    vushort4 o;
    o[0] = f2bf(v[0]); o[1] = f2bf(v[1]); o[2] = f2bf(v[2]); o[3] = f2bf(v[3]);
    ((vushort4*)h_bf)[idx] = o;
}

// ---- pack weight [K x 128] f32 into per-lane B-fragment bf16 layout ----
__device__ __forceinline__ void pack_one(const float* __restrict__ src,
                                         unsigned short* __restrict__ dst,
                                         int local, int KB) {
    int j = local & 7;
    int lane = (local >> 3) & 63;
    int rest = local >> 9;
    int kb = rest % KB;
    int t = rest / KB;
    int srow = kb * 32 + ((lane >> 4) << 3) + j;
    int scol = t * 16 + (lane & 15);
    dst[local] = f2bf(src[srow * 128 + scol]);
}

__global__ __launch_bounds__(256) void pack_w_kernel(
    const float* __restrict__ We1, const float* __restrict__ We2,
    const float* __restrict__ Wc1, const float* __restrict__ Wn1,
    const float* __restrict__ Wn2,
    unsigned short* __restrict__ We1p, unsigned short* __restrict__ We2p,
    unsigned short* __restrict__ Wc1p, unsigned short* __restrict__ Wn1p,
    unsigned short* __restrict__ Wn2p) {
    int idx = blockIdx.x * 256 + threadIdx.x;
    if (idx < 32768)       pack_one(We1, We1p, idx, 8);
    else if (idx < 49152)  pack_one(We2, We2p, idx - 32768, 4);
    else if (idx < 65536)  pack_one(Wc1, Wc1p, idx - 49152, 4);
    else if (idx < 98304)  pack_one(Wn1, Wn1p, idx - 65536, 8);
    else                   pack_one(Wn2, Wn2p, idx - 98304, 4);
}

// ---- histogram of edge rows (int counts) ----
__global__ __launch_bounds__(256) void hist_kernel(const int* __restrict__ ei,
                                                   int* __restrict__ cnt) {
    int e = blockIdx.x * 256 + threadIdx.x;
    if (e < NE) atomicAdd(&cnt[ei[e]], 1);
}

// ---- edge kernel: 64 edges/block, 4 waves x 16 edges, ZERO barriers ----
__global__ __launch_bounds__(256, 5) void edge_kernel(
    const float* __restrict__ x, const int* __restrict__ ei,
    const unsigned short* __restrict__ h_bf,
    const unsigned short* __restrict__ We1p, const unsigned short* __restrict__ We2p,
    const unsigned short* __restrict__ Wc1p,
    const float* __restrict__ We1, const float* __restrict__ be1,
    const float* __restrict__ be2, const float* __restrict__ bc1,
    const float* __restrict__ Wc2, const float* __restrict__ bc2,
    float* __restrict__ dxsum, float* __restrict__ agg) {

    __shared__ __align__(16) unsigned short s_ef[64 * 136];  // wave-local rows only
    __shared__ float s_rel[64 * 4];
    __shared__ int s_row[64];
    __shared__ int s_col[64];

    const int tid = threadIdx.x;
    const int wave = tid >> 6, lane = tid & 63;
    const int li = lane & 15, grp = lane >> 4;
    const int ebase = blockIdx.x * 64;
    const int el = wave * 16 + li;

    // per-wave staging: lanes 0..15 stage this wave's 16 edges (wave-local LDS;
    // same-wave write->read ordered by lgkmcnt, no barrier needed)
    if (lane < 16) {
        int e = ebase + wave * 16 + lane;
        int r = ei[e], c = ei[NE + e];
        s_row[wave * 16 + lane] = r;
        s_col[wave * 16 + lane] = c;
        float d0 = x[r * 3 + 0] - x[c * 3 + 0];
        float d1 = x[r * 3 + 1] - x[c * 3 + 1];
        float d2v = x[r * 3 + 2] - x[c * 3 + 2];
        s_rel[(wave * 16 + lane) * 4 + 0] = d0;
        s_rel[(wave * 16 + lane) * 4 + 1] = d1;
        s_rel[(wave * 16 + lane) * 4 + 2] = d2v;
        s_rel[(wave * 16 + lane) * 4 + 3] = d0 * d0 + d1 * d1 + d2v * d2v;
    }

    const vf32x4 vzero = {0.f, 0.f, 0.f, 0.f};

    // ---- direct global A-fragments [h[row] | h[col]] ----
    vbf16x8 af[8];
    {
        const unsigned short* pr = h_bf + (size_t)s_row[el] * 128 + grp * 8;
        const unsigned short* pc = h_bf + (size_t)s_col[el] * 128 + grp * 8;
#pragma unroll
        for (int kb = 0; kb < 4; kb++) af[kb] = *(const vbf16x8*)(pr + kb * 32);
#pragma unroll
        for (int kb = 0; kb < 4; kb++) af[4 + kb] = *(const vbf16x8*)(pc + kb * 32);
    }

    // ---- layer 1: [64,256] @ We1 ----
    vf32x4 acc[8];
#pragma unroll
    for (int t = 0; t < 8; t++) acc[t] = vzero;
#pragma unroll
    for (int kb = 0; kb < 8; kb++) {
#pragma unroll
        for (int t = 0; t < 8; t++) {
            vbf16x8 b = *(const vbf16x8*)(We1p + ((t * 8 + kb) * 64 + lane) * 8);
            acc[t] = __builtin_amdgcn_mfma_f32_16x16x32_bf16(af[kb], b, acc[t], 0, 0, 0);
        }
    }
    float d2[4];
#pragma unroll
    for (int r = 0; r < 4; r++) d2[r] = s_rel[(wave * 16 + grp * 4 + r) * 4 + 3];
#pragma unroll
    for (int t = 0; t < 8; t++) {
        int col = t * 16 + li;
        float b1 = be1[col], wl = We1[256 * 128 + col];
#pragma unroll
        for (int r = 0; r < 4; r++) {
            float v = silu(acc[t][r] + b1 + d2[r] * wl);
            s_ef[(wave * 16 + grp * 4 + r) * 136 + col] = f2bf(v);
        }
    }
    // no barrier: s_ef rows are wave-local

    // ---- layer 2: @ We2 ----
#pragma unroll
    for (int t = 0; t < 8; t++) acc[t] = vzero;
    {
        const unsigned short* arow = s_ef + (wave * 16 + li) * 136 + grp * 8;
#pragma unroll
        for (int kb = 0; kb < 4; kb++) {
            vbf16x8 a = *(const vbf16x8*)(arow + kb * 32);
#pragma unroll
            for (int t = 0; t < 8; t++) {
                vbf16x8 b = *(const vbf16x8*)(We2p + ((t * 4 + kb) * 64 + lane) * 8);
                acc[t] = __builtin_amdgcn_mfma_f32_16x16x32_bf16(a, b, acc[t], 0, 0, 0);
            }
        }
    }
    float ef_reg[8][4];
#pragma unroll
    for (int t = 0; t < 8; t++) {
        int col = t * 16 + li;
        float b2 = be2[col];
#pragma unroll
        for (int r = 0; r < 4; r++) {
            ef_reg[t][r] = silu(acc[t][r] + b2);
            s_ef[(wave * 16 + grp * 4 + r) * 136 + col] = f2bf(ef_reg[t][r]);
        }
    }

    // ---- gate: silu(ef @ Wc1 + bc1) . Wc2 + bc2 ----
#pragma unroll
    for (int t = 0; t < 8; t++) acc[t] = vzero;
    {
        const unsigned short* arow = s_ef + (wave * 16 + li) * 136 + grp * 8;
#pragma unroll
        for (int kb = 0; kb < 4; kb++) {
            vbf16x8 a = *(const vbf16x8*)(arow + kb * 32);
#pragma unroll
            for (int t = 0; t < 8; t++) {
                vbf16x8 b = *(const vbf16x8*)(Wc1p + ((t * 4 + kb) * 64 + lane) * 8);
                acc[t] = __builtin_amdgcn_mfma_f32_16x16x32_bf16(a, b, acc[t], 0, 0, 0);
            }
        }
    }
    float gp[4] = {0.f, 0.f, 0.f, 0.f};
#pragma unroll
    for (int t = 0; t < 8; t++) {
        int col = t * 16 + li;
        float bc = bc1[col], w2 = Wc2[col];
#pragma unroll
        for (int r = 0; r < 4; r++) gp[r] += silu(acc[t][r] + bc) * w2;
    }
#pragma unroll
    for (int r = 0; r < 4; r++) {
#pragma unroll
        for (int d = 1; d < 16; d <<= 1) gp[r] += __shfl_xor(gp[r], d, 16);
        gp[r] += bc2[0];
    }

    // ---- scatter (atomics, at the very end so nothing waits behind them) ----
#pragma unroll
    for (int r = 0; r < 4; r++) {
        int e2 = wave * 16 + grp * 4 + r;
        int node = s_row[e2];
#pragma unroll
        for (int t = 0; t < 8; t++)
            atomicAdd(&agg[(size_t)node * 128 + t * 16 + li], ef_reg[t][r]);
        if (li < 3)
            atomicAdd(&dxsum[node * 3 + li], s_rel[e2 * 4 + li] * gp[r]);
    }
}

// ---- node kernel: 64 nodes per block, ZERO barriers ----
__global__ __launch_bounds__(256, 4) void node_kernel(
    const float* __restrict__ x, const float* __restrict__ h32,
    const unsigned short* __restrict__ h_bf,
    const int* __restrict__ cnt, const float* __restrict__ dxsum,
    const float* __restrict__ agg,
    const unsigned short* __restrict__ Wn1p, const unsigned short* __restrict__ Wn2p,
    const float* __restrict__ bn1, const float* __restrict__ bn2,
    const float* __restrict__ gamma, const float* __restrict__ beta,
    float* __restrict__ out) {

    __shared__ __align__(16) unsigned short s_agg[64 * 136];
    __shared__ __align__(16) unsigned short s_ef[64 * 136];

    const int tid = threadIdx.x;
    const int nbase = blockIdx.x * 64;
    const int wave = tid >> 6, lane = tid & 63;
    const int li = lane & 15, grp = lane >> 4;

    // x_out = x + dx/cnt (independent global work)
    {
        int idx = blockIdx.x * 192 + tid;
        if (tid < 192 && idx < NN * 3) {
            int node = idx / 3;
            float cf = fmaxf((float)cnt[node], 1.0f);
            out[idx] = x[idx] + dxsum[idx] / cf;
        }
    }
    // per-wave staging of this wave's 16 agg rows (wave-local; no barrier)
#pragma unroll
    for (int it = 0; it < 8; it++) {
        int idx = it * 64 + lane;
        int rloc = idx >> 5, q = idx & 31;
        int node = nbase + wave * 16 + rloc;
        if (node >= NN) node = NN - 1;
        float inv = 1.0f / fmaxf((float)cnt[node], 1.0f);
        vf32x4 v = *(const vf32x4*)(agg + (size_t)node * 128 + q * 4);
        vushort4 o;
        o[0] = f2bf(v[0] * inv); o[1] = f2bf(v[1] * inv);
        o[2] = f2bf(v[2] * inv); o[3] = f2bf(v[3] * inv);
        *(vushort4*)(&s_agg[(wave * 16 + rloc) * 136 + q * 4]) = o;
    }

    const vf32x4 vzero = {0.f, 0.f, 0.f, 0.f};
    int mynode = nbase + wave * 16 + li;
    if (mynode >= NN) mynode = NN - 1;

    vbf16x8 af[8];
    {
        const unsigned short* ph = h_bf + (size_t)mynode * 128 + grp * 8;
#pragma unroll
        for (int kb = 0; kb < 4; kb++) af[kb] = *(const vbf16x8*)(ph + kb * 32);
        const unsigned short* pa = s_agg + (wave * 16 + li) * 136 + grp * 8;
#pragma unroll
        for (int kb = 0; kb < 4; kb++) af[4 + kb] = *(const vbf16x8*)(pa + kb * 32);
    }
    vf32x4 acc[8];
#pragma unroll
    for (int t = 0; t < 8; t++) acc[t] = vzero;
#pragma unroll
    for (int kb = 0; kb < 8; kb++) {
#pragma unroll
        for (int t = 0; t < 8; t++) {
            vbf16x8 b = *(const vbf16x8*)(Wn1p + ((t * 8 + kb) * 64 + lane) * 8);
            acc[t] = __builtin_amdgcn_mfma_f32_16x16x32_bf16(af[kb], b, acc[t], 0, 0, 0);
        }
    }
#pragma unroll
    for (int t = 0; t < 8; t++) {
        int col = t * 16 + li;
        float b1 = bn1[col];
#pragma unroll
        for (int r = 0; r < 4; r++) {
            float v = silu(acc[t][r] + b1);
            s_ef[(wave * 16 + grp * 4 + r) * 136 + col] = f2bf(v);
        }
    }
    // no barrier: wave-local

#pragma unroll
    for (int t = 0; t < 8; t++) acc[t] = vzero;
    {
        const unsigned short* arow = s_ef + (wave * 16 + li) * 136 + grp * 8;
#pragma unroll
        for (int kb = 0; kb < 4; kb++) {
            vbf16x8 a = *(const vbf16x8*)(arow + kb * 32);
#pragma unroll
            for (int t = 0; t < 8; t++) {
                vbf16x8 b = *(const vbf16x8*)(Wn2p + ((t * 4 + kb) * 64 + lane) * 8);
                acc[t] = __builtin_amdgcn_mfma_f32_16x16x32_bf16(a, b, acc[t], 0, 0, 0);
            }
        }
    }
    float h2v[8][4];
    float sum[4] = {0.f, 0.f, 0.f, 0.f}, sq[4] = {0.f, 0.f, 0.f, 0.f};
#pragma unroll
    for (int t = 0; t < 8; t++) {
        int col = t * 16 + li;
        float b2 = bn2[col];
#pragma unroll
        for (int r = 0; r < 4; r++) {
            int node = nbase + wave * 16 + grp * 4 + r;
            int nc = node < NN ? node : NN - 1;
            float v = acc[t][r] + b2 + h32[(size_t)nc * 128 + col];
            h2v[t][r] = v;
            sum[r] += v;
            sq[r] += v * v;
        }
    }
    float mu[4], rstd[4];
#pragma unroll
    for (int r = 0; r < 4; r++) {
#pragma unroll
        for (int d = 1; d < 16; d <<= 1) {
            sum[r] += __shfl_xor(sum[r], d, 16);
            sq[r] += __shfl_xor(sq[r], d, 16);
        }
        mu[r] = sum[r] * (1.0f / 128.0f);
        float var = sq[r] * (1.0f / 128.0f) - mu[r] * mu[r];
        rstd[r] = rsqrtf(var + 1e-5f);
    }
#pragma unroll
    for (int t = 0; t < 8; t++) {
        int col = t * 16 + li;
        float g = gamma[col], bt = beta[col];
#pragma unroll
        for (int r = 0; r < 4; r++) {
            int node = nbase + wave * 16 + grp * 4 + r;
            if (node < NN) {
                float vn = (h2v[t][r] - mu[r]) * rstd[r] * g + bt;
                out[NN * 3 + (size_t)node * 128 + col] = silu(vn);
            }
        }
    }
}

extern "C" void kernel_launch(void* const* d_in, const int* in_sizes, int n_in,
                              void* d_out, int out_size, void* d_ws, size_t ws_size,
                              hipStream_t stream) {
    const float* x     = (const float*)d_in[0];
    const float* h     = (const float*)d_in[1];
    const int* ei      = (const int*)d_in[2];
    const float* We1   = (const float*)d_in[3];
    const float* be1   = (const float*)d_in[4];
    const float* We2   = (const float*)d_in[5];
    const float* be2   = (const float*)d_in[6];
    const float* Wc1   = (const float*)d_in[7];
    const float* bc1   = (const float*)d_in[8];
    const float* Wc2   = (const float*)d_in[9];
    const float* bc2   = (const float*)d_in[10];
    const float* Wn1   = (const float*)d_in[11];
    const float* bn1   = (const float*)d_in[12];
    const float* Wn2   = (const float*)d_in[13];
    const float* bn2   = (const float*)d_in[14];
    const float* gamma = (const float*)d_in[15];
    const float* beta  = (const float*)d_in[16];
    float* out = (float*)d_out;

    char* ws = (char*)d_ws;
    float* agg            = (float*)(ws + OFF_AGG);
    int* cnt              = (int*)(ws + OFF_CNT);
    float* dxsum          = (float*)(ws + OFF_DX);
    unsigned short* h_bf  = (unsigned short*)(ws + OFF_HBF);
    unsigned short* We1p  = (unsigned short*)(ws + OFF_WE1P);
    unsigned short* We2p  = (unsigned short*)(ws + OFF_WE2P);
    unsigned short* Wc1p  = (unsigned short*)(ws + OFF_WC1P);
    unsigned short* Wn1p  = (unsigned short*)(ws + OFF_WN1P);
    unsigned short* Wn2p  = (unsigned short*)(ws + OFF_WN2P);

    hipMemsetAsync(ws, 0, ZBYTES, stream);
    h2bf_kernel<<<6250, 256, 0, stream>>>(h, h_bf);
    pack_w_kernel<<<448, 256, 0, stream>>>(We1, We2, Wc1, Wn1, Wn2,
                                           We1p, We2p, Wc1p, Wn1p, Wn2p);
    hist_kernel<<<NE / 256, 256, 0, stream>>>(ei, cnt);
    edge_kernel<<<NE / 64, 256, 0, stream>>>(x, ei, h_bf, We1p, We2p, Wc1p,
                                             We1, be1, be2, bc1, Wc2, bc2,
                                             dxsum, agg);
    node_kernel<<<(NN + 63) / 64, 256, 0, stream>>>(x, h, h_bf, cnt, dxsum, agg,
                                                    Wn1p, Wn2p, bn1, bn2, gamma, beta, out);
}